// Round 1
// baseline (1758.231 us; speedup 1.0000x reference)
//
#include <hip/hip_runtime.h>
#include <hip/hip_bf16.h>

// CfC cell: out = combine(heads(lecun(lecun(concat(in,hx)@W0)@W1) @ [Wff1|Wff2|Wta|Wtb]))
// Strategy: bf16 MFMA GEMMs (m97 128x128/BK=32 structure), fused head epilogue.

typedef unsigned short u16;
typedef __bf16 bf16x8_t __attribute__((ext_vector_type(8)));
typedef float f32x4_t __attribute__((ext_vector_type(4)));
typedef u16 u16x8_t __attribute__((ext_vector_type(8)));

#define M_TOTAL 131072  // B*T = 128*1024

__device__ __forceinline__ u16 f2bf(float f) {
  union { float f; unsigned u; } v; v.f = f;
  unsigned r = v.u + 0x7FFFu + ((v.u >> 16) & 1u);  // RNE
  return (u16)(r >> 16);
}

__device__ __forceinline__ float fast_tanh(float x) {
  x = fminf(15.f, fmaxf(-15.f, x));
  float e = __expf(2.f * x);
  return (e - 1.f) * __builtin_amdgcn_rcpf(e + 1.f);
}

__device__ __forceinline__ float fast_sigmoid(float x) {
  return __builtin_amdgcn_rcpf(1.f + __expf(-x));  // exp(-x)->inf => rcp->0, safe
}

__device__ __forceinline__ void gload_lds16(const void* g, void* l) {
  __builtin_amdgcn_global_load_lds(
      (const __attribute__((address_space(1))) unsigned int*)g,
      (__attribute__((address_space(3))) unsigned int*)l,
      16, 0, 0);
}

// ---------------- prep kernels ----------------

// Xcat[m][0:256)=input[m], [256:768)=hx[m], bf16
__global__ void prep_x(const float* __restrict__ inp, const float* __restrict__ hx,
                       u16* __restrict__ X) {
  const int total = M_TOTAL * 96;  // 96 chunks of 8 cols per row
  int stride = gridDim.x * blockDim.x;
  for (int v = blockIdx.x * blockDim.x + threadIdx.x; v < total; v += stride) {
    int m = v / 96; int c = v - m * 96;
    const float* src = (c < 32) ? (inp + (size_t)m * 256 + (c << 3))
                                : (hx + (size_t)m * 512 + ((size_t)(c - 32) << 3));
    f32x4_t a = *(const f32x4_t*)src;
    f32x4_t b = *(const f32x4_t*)(src + 4);
    u16x8_t o;
    o[0]=f2bf(a[0]); o[1]=f2bf(a[1]); o[2]=f2bf(a[2]); o[3]=f2bf(a[3]);
    o[4]=f2bf(b[0]); o[5]=f2bf(b[1]); o[6]=f2bf(b[2]); o[7]=f2bf(b[3]);
    *(u16x8_t*)(X + (size_t)m * 768 + (c << 3)) = o;
  }
}

// WT[(n*RS+RO)][k] = bf16(W[k][n]); W is [K][N] fp32, WT rows are k-contiguous
__global__ void prep_wt(const float* __restrict__ W, u16* __restrict__ WT,
                        int K, int N, int RS, int RO) {
  int id = blockIdx.x * blockDim.x + threadIdx.x;
  int k8s = K >> 3;
  int total = N * k8s;
  if (id >= total) return;
  int n = id / k8s;
  int k0 = (id - n * k8s) << 3;
  u16x8_t o;
#pragma unroll
  for (int i = 0; i < 8; ++i) o[i] = f2bf(W[(size_t)(k0 + i) * N + n]);
  *(u16x8_t*)(WT + ((size_t)n * RS + RO) * K + k0) = o;
}

// interleaved head bias: bi[4h+j] = b_j[h]
__global__ void prep_bias(const float* __restrict__ b1, const float* __restrict__ b2,
                          const float* __restrict__ b3, const float* __restrict__ b4,
                          float* __restrict__ bi) {
  int h = blockIdx.x * blockDim.x + threadIdx.x;
  if (h < 512) {
    bi[(h << 2) + 0] = b1[h];
    bi[(h << 2) + 1] = b2[h];
    bi[(h << 2) + 2] = b3[h];
    bi[(h << 2) + 3] = b4[h];
  }
}

// ---------------- GEMM ----------------
// C = A[M,K](bf16) * BT[NI,K]^T (bf16), 128x128 tile, BK=32, 4 waves (2x2 of 64x64).
// EPI=0: C -> lecun_tanh(C+bias) as bf16 [M,NI]
// EPI=1: interleaved heads (col=4h+head): out[m][h] = ff1*(1-s)+s*ff2, fp32 [M,NI/4]
template<int K, int NI, int EPI>
__global__ __launch_bounds__(256, 2)
void gemm_k(const u16* __restrict__ A, const u16* __restrict__ BT,
            const float* __restrict__ bias, const float* __restrict__ ts,
            void* __restrict__ Cout)
{
  constexpr int NT = NI / 128;
  constexpr int SMEM_BYTES = (EPI == 1) ? 65536 : 16384;
  __shared__ __align__(16) char smem[SMEM_BYTES];
  // As: [128][32] bf16 at smem+0 (8KB); Bs: [128][32] bf16 at smem+8192 (8KB)

  const int bid = blockIdx.x;
  const int mt = bid / NT;
  const int nt = bid - mt * NT;
  const int tid = threadIdx.x;
  const int w = tid >> 6;
  const int l = tid & 63;

  const int tile_m = mt * 128;
  const int tile_n = nt * 128;

  // staging: 8 chunks of 1024B per tile; wave w does chunks 2w,2w+1.
  // chunk c covers rows c*16..c*16+15, linear LDS = global_load_lds lane order.
  const int srow = (w << 5) + (l >> 2);     // row for chunk 2w
  const int scol = (l & 3) << 3;            // bf16 col within BK
  const u16* gA0 = A + (size_t)(tile_m + srow) * K + scol;
  const u16* gA1 = gA0 + (size_t)16 * K;
  const u16* gB0 = BT + (size_t)(tile_n + srow) * K + scol;
  const u16* gB1 = gB0 + (size_t)16 * K;
  char* lA0 = smem + (w << 11);
  char* lA1 = lA0 + 1024;
  char* lB0 = smem + 8192 + (w << 11);
  char* lB1 = lB0 + 1024;

  f32x4_t acc[4][4];
#pragma unroll
  for (int i = 0; i < 4; ++i)
#pragma unroll
    for (int j = 0; j < 4; ++j) acc[i][j] = f32x4_t{0.f, 0.f, 0.f, 0.f};

  const int wr = (w >> 1) << 6;   // wave row offset (0/64)
  const int wc = (w & 1) << 6;    // wave col offset (0/64)
  // fragment byte offset within a 16-row block: row=(l&15), kblock=(l>>4)
  const int fo = ((l & 15) << 6) + ((l >> 4) << 4);
  const char* aBase = (const char*)smem + wr * 64 + fo;
  const char* bBase = (const char*)smem + 8192 + wc * 64 + fo;

  for (int kt = 0; kt < K; kt += 32) {
    gload_lds16(gA0, lA0);
    gload_lds16(gA1, lA1);
    gload_lds16(gB0, lB0);
    gload_lds16(gB1, lB1);
    gA0 += 32; gA1 += 32; gB0 += 32; gB1 += 32;
    __syncthreads();  // drains vmcnt(0): tiles resident
    bf16x8_t af[4], bfr[4];
#pragma unroll
    for (int m = 0; m < 4; ++m) af[m] = *(const bf16x8_t*)(aBase + m * 1024);
#pragma unroll
    for (int n = 0; n < 4; ++n) bfr[n] = *(const bf16x8_t*)(bBase + n * 1024);
#pragma unroll
    for (int m = 0; m < 4; ++m)
#pragma unroll
      for (int n = 0; n < 4; ++n)
        acc[m][n] = __builtin_amdgcn_mfma_f32_16x16x32_bf16(af[m], bfr[n], acc[m][n], 0, 0, 0);
    __syncthreads();  // all waves done reading before next stage overwrites
  }

  // C/D layout (m89-verified): col = lane&15, row = (lane>>4)*4 + reg
  if constexpr (EPI == 0) {
    u16* C = (u16*)Cout;
    const int col0 = tile_n + wc + (l & 15);
    const int row0 = tile_m + wr + ((l >> 4) << 2);
#pragma unroll
    for (int n = 0; n < 4; ++n) {
      const float bv = bias[col0 + n * 16];
#pragma unroll
      for (int m = 0; m < 4; ++m) {
#pragma unroll
        for (int j = 0; j < 4; ++j) {
          float v = acc[m][n][j] + bv;
          float t = 1.7159f * fast_tanh(0.666f * v);
          C[(size_t)(row0 + m * 16 + j) * NI + (col0 + n * 16)] = f2bf(t);
        }
      }
    }
  } else {
    // dump wave's 64x64 fp32 tile to LDS, re-read as (h, head0..3) groups
    float* epi = (float*)(smem) + (w << 12);  // 16KB per wave
    const int rl = (l >> 4) << 2;
#pragma unroll
    for (int m = 0; m < 4; ++m)
#pragma unroll
      for (int n = 0; n < 4; ++n)
#pragma unroll
        for (int j = 0; j < 4; ++j)
          epi[(m * 16 + rl + j) * 64 + n * 16 + (l & 15)] = acc[m][n][j];
    __syncthreads();
    float* out = (float*)Cout;
    const int hl = l & 15;
    const int rb = l >> 4;
    const int h_g = ((tile_n + wc) >> 2) + hl;
    const f32x4_t bv = *(const f32x4_t*)(bias + (h_g << 2));
#pragma unroll
    for (int rr = 0; rr < 16; ++rr) {
      const int r = (rb << 4) + rr;
      f32x4_t v4 = *(const f32x4_t*)(epi + r * 64 + (hl << 2));
      const int row_g = tile_m + wr + r;
      const float tsv = ts[row_g];
      float ff1 = fast_tanh(v4[0] + bv[0]);
      float ff2 = fast_tanh(v4[1] + bv[1]);
      float s = fast_sigmoid((v4[2] + bv[2]) * tsv + (v4[3] + bv[3]));
      out[(size_t)row_g * 512 + h_g] = ff1 * (1.f - s) + s * ff2;
    }
  }
}

// ---------------- launch ----------------

extern "C" void kernel_launch(void* const* d_in, const int* in_sizes, int n_in,
                              void* d_out, int out_size, void* d_ws, size_t ws_size,
                              hipStream_t stream) {
  const float* input = (const float*)d_in[0];
  const float* hx    = (const float*)d_in[1];
  const float* ts    = (const float*)d_in[2];
  const float* W0    = (const float*)d_in[3];
  const float* b0    = (const float*)d_in[4];
  const float* W1    = (const float*)d_in[5];
  const float* b1    = (const float*)d_in[6];
  const float* Wff1  = (const float*)d_in[7];
  const float* bff1  = (const float*)d_in[8];
  const float* Wff2  = (const float*)d_in[9];
  const float* bff2  = (const float*)d_in[10];
  const float* Wta   = (const float*)d_in[11];
  const float* bta   = (const float*)d_in[12];
  const float* Wtb   = (const float*)d_in[13];
  const float* btb   = (const float*)d_in[14];

  // workspace layout (bytes):
  //   buf0 [0, 268435456): Xcat bf16 [M,768] (201MB), later reused as X2 bf16 [M,1024]
  //   X1   [268435456, 536870912): bf16 [M,1024]
  //   W0T  [536870912): bf16 [1024][768]
  //   W1T  [538443776): bf16 [1024][1024]
  //   WhT  [540540928): bf16 [2048][1024] interleaved col=4h+head
  //   biasi[544735232): fp32 [2048]
  const size_t WS_NEEDED = 544743424ull;
  if (ws_size < WS_NEEDED) return;
  char* ws = (char*)d_ws;
  u16* Xcat = (u16*)(ws);
  u16* X2   = (u16*)(ws);
  u16* X1   = (u16*)(ws + 268435456ull);
  u16* W0T  = (u16*)(ws + 536870912ull);
  u16* W1T  = (u16*)(ws + 538443776ull);
  u16* WhT  = (u16*)(ws + 540540928ull);
  float* biasi = (float*)(ws + 544735232ull);

  prep_x<<<2048, 256, 0, stream>>>(input, hx, Xcat);
  prep_wt<<<(1024 * 96 + 255) / 256, 256, 0, stream>>>(W0, W0T, 768, 1024, 1, 0);
  prep_wt<<<(1024 * 128 + 255) / 256, 256, 0, stream>>>(W1, W1T, 1024, 1024, 1, 0);
  prep_wt<<<(512 * 128 + 255) / 256, 256, 0, stream>>>(Wff1, WhT, 1024, 512, 4, 0);
  prep_wt<<<(512 * 128 + 255) / 256, 256, 0, stream>>>(Wff2, WhT, 1024, 512, 4, 1);
  prep_wt<<<(512 * 128 + 255) / 256, 256, 0, stream>>>(Wta,  WhT, 1024, 512, 4, 2);
  prep_wt<<<(512 * 128 + 255) / 256, 256, 0, stream>>>(Wtb,  WhT, 1024, 512, 4, 3);
  prep_bias<<<2, 256, 0, stream>>>(bff1, bff2, bta, btb, biasi);

  // GEMM0: [M,768] @ [768,1024] -> X1
  gemm_k<768, 1024, 0><<<(M_TOTAL / 128) * 8, 256, 0, stream>>>(Xcat, W0T, b0, nullptr, X1);
  // GEMM1: [M,1024] @ [1024,1024] -> X2 (reuses buf0)
  gemm_k<1024, 1024, 0><<<(M_TOTAL / 128) * 8, 256, 0, stream>>>(X1, W1T, b1, nullptr, X2);
  // heads: [M,1024] @ [1024,2048] interleaved, fused combine -> out fp32 [M,512]
  gemm_k<1024, 2048, 1><<<(M_TOTAL / 128) * 16, 256, 0, stream>>>(X2, WhT, biasi, ts, d_out);
}

// Round 2
// 1212.955 us; speedup vs baseline: 1.4495x; 1.4495x over previous
//
#include <hip/hip_runtime.h>
#include <hip/hip_bf16.h>

// CfC cell via three bf16 MFMA GEMMs in the 256x256 8-phase schedule
// (T2 st_16x32 LDS swizzle + T3/T4 counted vmcnt + T5 setprio).
// Heads interleaved per 16-col block so the combine epilogue is lane-local.

typedef unsigned short u16;
typedef __bf16 bf16x8_t __attribute__((ext_vector_type(8)));
typedef float f32x4_t __attribute__((ext_vector_type(4)));
typedef u16 u16x8_t __attribute__((ext_vector_type(8)));

#define M_TOTAL 131072  // B*T = 128*1024

__device__ __forceinline__ u16 f2bf(float f) {
  union { float f; unsigned u; } v; v.f = f;
  unsigned r = v.u + 0x7FFFu + ((v.u >> 16) & 1u);  // RNE
  return (u16)(r >> 16);
}

__device__ __forceinline__ float fast_tanh(float x) {
  x = fminf(15.f, fmaxf(-15.f, x));
  float e = __expf(2.f * x);
  return (e - 1.f) * __builtin_amdgcn_rcpf(e + 1.f);
}

__device__ __forceinline__ float fast_sigmoid(float x) {
  return __builtin_amdgcn_rcpf(1.f + __expf(-x));
}

__device__ __forceinline__ void gload_lds16(const void* g, void* l) {
  __builtin_amdgcn_global_load_lds(
      (const __attribute__((address_space(1))) unsigned int*)g,
      (__attribute__((address_space(3))) unsigned int*)l,
      16, 0, 0);
}

// ---------------- prep kernels ----------------

__global__ void prep_x(const float* __restrict__ inp, const float* __restrict__ hx,
                       u16* __restrict__ X) {
  const int total = M_TOTAL * 96;
  int stride = gridDim.x * blockDim.x;
  for (int v = blockIdx.x * blockDim.x + threadIdx.x; v < total; v += stride) {
    int m = v / 96; int c = v - m * 96;
    const float* src = (c < 32) ? (inp + (size_t)m * 256 + (c << 3))
                                : (hx + (size_t)m * 512 + ((size_t)(c - 32) << 3));
    f32x4_t a = *(const f32x4_t*)src;
    f32x4_t b = *(const f32x4_t*)(src + 4);
    u16x8_t o;
    o[0]=f2bf(a[0]); o[1]=f2bf(a[1]); o[2]=f2bf(a[2]); o[3]=f2bf(a[3]);
    o[4]=f2bf(b[0]); o[5]=f2bf(b[1]); o[6]=f2bf(b[2]); o[7]=f2bf(b[3]);
    *(u16x8_t*)(X + (size_t)m * 768 + (c << 3)) = o;
  }
}

// WT[row(n)][k] = bf16(W[k][n]); head<0: row=n; else head-interleave per 16-block.
__global__ void prep_wt(const float* __restrict__ W, u16* __restrict__ WT,
                        int K, int N, int head) {
  int id = blockIdx.x * blockDim.x + threadIdx.x;
  int k8s = K >> 3;
  int total = N * k8s;
  if (id >= total) return;
  int n = id / k8s;
  int k0 = (id - n * k8s) << 3;
  u16x8_t o;
#pragma unroll
  for (int i = 0; i < 8; ++i) o[i] = f2bf(W[(size_t)(k0 + i) * N + n]);
  int row = (head < 0) ? n : (((n >> 4) << 6) + head * 16 + (n & 15));
  *(u16x8_t*)(WT + (size_t)row * K + k0) = o;
}

__global__ void prep_bias(const float* __restrict__ b1, const float* __restrict__ b2,
                          const float* __restrict__ b3, const float* __restrict__ b4,
                          float* __restrict__ bi) {
  int h = blockIdx.x * blockDim.x + threadIdx.x;
  if (h < 512) {
    int base = ((h >> 4) << 6) + (h & 15);
    bi[base +  0] = b1[h];
    bi[base + 16] = b2[h];
    bi[base + 32] = b3[h];
    bi[base + 48] = b4[h];
  }
}

// ---------------- 256x256 8-phase GEMM ----------------
// C = A[M,K] * BT[NI,K]^T, bf16 in / fp32 acc. 512 thr = 8 waves (2Mx4N),
// per-wave 128x64. BK=64 (two 16x16x32 k-subtiles as LDS k-slabs).
// LDS: A[2buf][2slab][256][32] at 0, B same at 65536 -> 128 KiB.
// Swizzle: colbyte ^= ((row>>3)&1)<<5 (st_16x32); stage = linear dest +
// inverse-swizzled global source (rule 21).

#define BARX()  do { __builtin_amdgcn_s_barrier(); __builtin_amdgcn_sched_barrier(0); } while(0)
#define LGKM0() do { asm volatile("s_waitcnt lgkmcnt(0)" ::: "memory"); __builtin_amdgcn_sched_barrier(0); } while(0)

template<int K, int NI, int EPI>
__global__ __launch_bounds__(512, 2)
void gemm256(const u16* __restrict__ A, const u16* __restrict__ BT,
             const float* __restrict__ bias, const float* __restrict__ ts,
             void* __restrict__ Cout)
{
  constexpr int NTn = NI / 256;
  constexpr int NITER = K / 128;           // 2 K-tiles (of 64) per iter
  constexpr int NWG = (M_TOTAL / 256) * NTn;
  __shared__ __align__(16) char smem[131072];

  const int bid0 = blockIdx.x;
  const int bid = (bid0 & 7) * (NWG >> 3) + (bid0 >> 3);   // XCD swizzle (NWG%8==0)
  const int mt = bid / NTn, nt = bid % NTn;
  const int tileM = mt * 256, tileN = nt * 256;

  const int tid = threadIdx.x;
  const int w = tid >> 6, l = tid & 63;
  const int wm = w >> 2, wn = w & 3;

  // ---- staging addressing: chunk c = 2w+j (1024B), slab kk=c>>3,
  // rows (c&7)*16 + (l>>2), colbyte ((l&3)<<4) ^ ((l>>5)&1)<<5 (inverse swz)
  const int c0 = w * 2, c1 = w * 2 + 1;
  const int kkS0 = c0 >> 3, kkS1 = c1 >> 3;
  const int rS0 = (c0 & 7) * 16 + (l >> 2);
  const int rS1 = (c1 & 7) * 16 + (l >> 2);
  const int cbS = ((l & 3) << 4) ^ (((l >> 5) & 1) << 5);
  const int cA0 = (c0 & 7) * 1024, cA1 = (c1 & 7) * 1024;
  const u16* aSrc = A + (size_t)tileM * K + (cbS >> 1);
  const u16* bSrc = BT + (size_t)tileN * K + (cbS >> 1);

  // ---- fragment read addressing (swz on read side)
  const int colRs = ((l >> 4) * 16) ^ (((l >> 3) & 1) << 5);
  const int aRowB = (wm * 128 + (l & 15)) * 64;
  const int bRowB = 65536 + (wn * 64 + (l & 15)) * 64;

  // bias prefetch (issued before stages: oldest vmcnt entries, drains first)
  const int colBase = tileN + wn * 64 + (l & 15);
  float bv[4];
  bv[0] = bias[colBase];      bv[1] = bias[colBase + 16];
  bv[2] = bias[colBase + 32]; bv[3] = bias[colBase + 48];

  f32x4_t acc[8][4];
#pragma unroll
  for (int i = 0; i < 8; ++i)
#pragma unroll
    for (int j = 0; j < 4; ++j) acc[i][j] = f32x4_t{0.f, 0.f, 0.f, 0.f};

  bf16x8_t af[4][2], b01[2][2], b23[2][2];

#define STAGE_A(d, h, t) do { \
    gload_lds16(aSrc + (size_t)((h)*128 + rS0) * K + (t)*64 + kkS0*32, \
                smem + (d)*32768 + kkS0*16384 + (h)*8192 + cA0); \
    gload_lds16(aSrc + (size_t)((h)*128 + rS1) * K + (t)*64 + kkS1*32, \
                smem + (d)*32768 + kkS1*16384 + (h)*8192 + cA1); } while(0)

#define STAGE_B(d, h, t) do { \
    gload_lds16(bSrc + (size_t)((h)*128 + rS0) * K + (t)*64 + kkS0*32, \
                smem + 65536 + (d)*32768 + kkS0*16384 + (h)*8192 + cA0); \
    gload_lds16(bSrc + (size_t)((h)*128 + rS1) * K + (t)*64 + kkS1*32, \
                smem + 65536 + (d)*32768 + kkS1*16384 + (h)*8192 + cA1); } while(0)

#define READ_A(d, mb) do { \
    _Pragma("unroll") for (int mm_ = 0; mm_ < 4; ++mm_) { \
      af[mm_][0] = *(const bf16x8_t*)(smem + (d)*32768 +         aRowB + ((mb)+mm_)*1024 + colRs); \
      af[mm_][1] = *(const bf16x8_t*)(smem + (d)*32768 + 16384 + aRowB + ((mb)+mm_)*1024 + colRs); } } while(0)

#define READ_B(d, breg, nb) do { \
    _Pragma("unroll") for (int nn_ = 0; nn_ < 2; ++nn_) { \
      breg[nn_][0] = *(const bf16x8_t*)(smem + (d)*32768 +         bRowB + ((nb)+nn_)*1024 + colRs); \
      breg[nn_][1] = *(const bf16x8_t*)(smem + (d)*32768 + 16384 + bRowB + ((nb)+nn_)*1024 + colRs); } } while(0)

#define MFMAQ(mb, nb, breg) do { \
    __builtin_amdgcn_s_setprio(1); \
    _Pragma("unroll") for (int kk_ = 0; kk_ < 2; ++kk_) \
      _Pragma("unroll") for (int mm_ = 0; mm_ < 4; ++mm_) \
        _Pragma("unroll") for (int nn_ = 0; nn_ < 2; ++nn_) \
          acc[(mb)+mm_][(nb)+nn_] = __builtin_amdgcn_mfma_f32_16x16x32_bf16( \
              af[mm_][kk_], breg[nn_][kk_], acc[(mb)+mm_][(nb)+nn_], 0, 0, 0); \
    __builtin_amdgcn_s_setprio(0); \
  } while(0)

  // prologue: buf0 = tile0 (all 4 halves), buf1 = tile1 B-halves
  STAGE_A(0, 0, 0); STAGE_A(0, 1, 0);
  STAGE_B(0, 0, 0); STAGE_B(0, 1, 0);
  STAGE_B(1, 0, 1); STAGE_B(1, 1, 1);
  asm volatile("s_waitcnt vmcnt(4)" ::: "memory");  // buf0 resident; buf1.B in flight
  BARX();

#pragma unroll 1
  for (int i = 0; i < NITER; ++i) {
    const int t1 = 2*i + 1, t2 = 2*i + 2, t3 = 2*i + 3;
    const bool more = (i + 1 < NITER);
    // ph1: A(buf0,m0-3)+B(buf0,n0-1); stage buf1.Ah0 (t1)
    READ_A(0, 0); READ_B(0, b01, 0);
    STAGE_A(1, 0, t1);
    BARX(); LGKM0(); MFMAQ(0, 0, b01); BARX();
    // ph2: B(buf0,n2-3); stage buf1.Ah1 (t1)
    READ_B(0, b23, 2);
    STAGE_A(1, 1, t1);
    BARX(); LGKM0(); MFMAQ(0, 2, b23); BARX();
    // ph3: A(buf0,m4-7); stage buf0.Bh0 (t2) [B(buf0) dead after ph2]
    READ_A(0, 4);
    if (more) STAGE_B(0, 0, t2);
    BARX(); LGKM0(); MFMAQ(4, 0, b01); BARX();
    // ph4: stage buf0.Bh1 (t2); vmcnt -> buf1 (t1) fully resident
    if (more) STAGE_B(0, 1, t2);
    BARX(); MFMAQ(4, 2, b23);
    if (more) { asm volatile("s_waitcnt vmcnt(4)" ::: "memory"); }
    else      { asm volatile("s_waitcnt vmcnt(0)" ::: "memory"); }
    BARX();
    // ph5: A(buf1,m0-3)+B(buf1,n0-1); stage buf0.Ah0 (t2) [A(buf0) dead after ph3]
    READ_A(1, 0); READ_B(1, b01, 0);
    if (more) STAGE_A(0, 0, t2);
    BARX(); LGKM0(); MFMAQ(0, 0, b01); BARX();
    // ph6: B(buf1,n2-3); stage buf0.Ah1 (t2)
    READ_B(1, b23, 2);
    if (more) STAGE_A(0, 1, t2);
    BARX(); LGKM0(); MFMAQ(0, 2, b23); BARX();
    // ph7: A(buf1,m4-7); stage buf1.Bh0 (t3) [B(buf1) dead after ph6]
    READ_A(1, 4);
    if (more) STAGE_B(1, 0, t3);
    BARX(); LGKM0(); MFMAQ(4, 0, b01); BARX();
    // ph8: stage buf1.Bh1 (t3); vmcnt -> buf0 (t2) fully resident
    if (more) STAGE_B(1, 1, t3);
    BARX(); MFMAQ(4, 2, b23);
    asm volatile("s_waitcnt vmcnt(4)" ::: "memory");
    BARX();
  }

  // ---------------- epilogue ----------------
  // C/D layout: col = lane&15, row = (lane>>4)*4 + reg (m89-verified)
  if constexpr (EPI == 0) {
    u16* C = (u16*)Cout;
#pragma unroll
    for (int m = 0; m < 8; ++m)
#pragma unroll
      for (int nn = 0; nn < 4; ++nn)
#pragma unroll
        for (int j = 0; j < 4; ++j) {
          const int row = tileM + wm*128 + m*16 + ((l >> 4) << 2) + j;
          float v = acc[m][nn][j] + bv[nn];
          float t = 1.7159f * fast_tanh(0.666f * v);
          C[(size_t)row * NI + colBase + nn*16] = f2bf(t);
        }
  } else {
    // heads interleaved per 16-col block: nn == head, h = (colblock>>6)*16 + (l&15)
    if (tid < 256) ((float*)smem)[tid] = ts[tileM + tid];
    __syncthreads();
    const int hg = ((tileN + wn*64) >> 6) * 16 + (l & 15);
    float* out = (float*)Cout;
#pragma unroll
    for (int m = 0; m < 8; ++m)
#pragma unroll
      for (int j = 0; j < 4; ++j) {
        const int rl = wm*128 + m*16 + ((l >> 4) << 2) + j;
        const float tsv = ((const float*)smem)[rl];
        float ff1 = fast_tanh(acc[m][0][j] + bv[0]);
        float ff2 = fast_tanh(acc[m][1][j] + bv[1]);
        float s = fast_sigmoid((acc[m][2][j] + bv[2]) * tsv + (acc[m][3][j] + bv[3]));
        out[(size_t)(tileM + rl) * 512 + hg] = ff1 + s * (ff2 - ff1);
      }
  }
#undef STAGE_A
#undef STAGE_B
#undef READ_A
#undef READ_B
#undef MFMAQ
}

// ---------------- launch ----------------

extern "C" void kernel_launch(void* const* d_in, const int* in_sizes, int n_in,
                              void* d_out, int out_size, void* d_ws, size_t ws_size,
                              hipStream_t stream) {
  const float* input = (const float*)d_in[0];
  const float* hx    = (const float*)d_in[1];
  const float* ts    = (const float*)d_in[2];
  const float* W0    = (const float*)d_in[3];
  const float* b0    = (const float*)d_in[4];
  const float* W1    = (const float*)d_in[5];
  const float* b1    = (const float*)d_in[6];
  const float* Wff1  = (const float*)d_in[7];
  const float* bff1  = (const float*)d_in[8];
  const float* Wff2  = (const float*)d_in[9];
  const float* bff2  = (const float*)d_in[10];
  const float* Wta   = (const float*)d_in[11];
  const float* bta   = (const float*)d_in[12];
  const float* Wtb   = (const float*)d_in[13];
  const float* btb   = (const float*)d_in[14];

  const size_t WS_NEEDED = 544743424ull;
  if (ws_size < WS_NEEDED) return;
  char* ws = (char*)d_ws;
  u16* Xcat = (u16*)(ws);                      // [M,768] bf16, reused as X2 [M,1024]
  u16* X2   = (u16*)(ws);
  u16* X1   = (u16*)(ws + 268435456ull);       // [M,1024] bf16
  u16* W0T  = (u16*)(ws + 536870912ull);       // [1024][768]
  u16* W1T  = (u16*)(ws + 538443776ull);       // [1024][1024]
  u16* WhT  = (u16*)(ws + 540540928ull);       // [2048][1024] head-interleaved
  float* biasi = (float*)(ws + 544735232ull);  // [2048]

  prep_x<<<2048, 256, 0, stream>>>(input, hx, Xcat);
  prep_wt<<<(1024 * 96 + 255) / 256, 256, 0, stream>>>(W0, W0T, 768, 1024, -1);
  prep_wt<<<(1024 * 128 + 255) / 256, 256, 0, stream>>>(W1, W1T, 1024, 1024, -1);
  prep_wt<<<(512 * 128 + 255) / 256, 256, 0, stream>>>(Wff1, WhT, 1024, 512, 0);
  prep_wt<<<(512 * 128 + 255) / 256, 256, 0, stream>>>(Wff2, WhT, 1024, 512, 1);
  prep_wt<<<(512 * 128 + 255) / 256, 256, 0, stream>>>(Wta,  WhT, 1024, 512, 2);
  prep_wt<<<(512 * 128 + 255) / 256, 256, 0, stream>>>(Wtb,  WhT, 1024, 512, 3);
  prep_bias<<<2, 256, 0, stream>>>(bff1, bff2, bta, btb, biasi);

  gemm256<768, 1024, 0><<<2048, 512, 0, stream>>>(Xcat, W0T, b0, nullptr, X1);
  gemm256<1024, 1024, 0><<<2048, 512, 0, stream>>>(X1, W1T, b1, nullptr, X2);
  gemm256<1024, 2048, 1><<<4096, 512, 0, stream>>>(X2, WhT, biasi, ts, d_out);
}